// Round 1
// baseline (327.511 us; speedup 1.0000x reference)
//
#include <hip/hip_runtime.h>

// out[e,b,o] = sum_n x[e,b,n]*W[e,o,n] + b[e,o],  E=50000, B=512, N=O=2.
// Flat layouts: x/out are E*B*2 floats (identical shape), W is E*4, b is E*2.
// One thread handles one float4 = 2 batch rows. 256 float4 per edge -> e = i>>8
// is wave-uniform, so W/b loads are broadcast and cache-resident.

__global__ __launch_bounds__(256) void plt_kernel(
    const float4* __restrict__ x,
    const float4* __restrict__ W,
    const float2* __restrict__ b,
    float4* __restrict__ out,
    int total)  // total float4s = E*B*2/4
{
    int i = blockIdx.x * blockDim.x + threadIdx.x;
    if (i >= total) return;

    int e = i >> 8;           // 256 float4 per edge (B*N*4B / 16B)
    float4 xv = x[i];         // x[b,0], x[b,1], x[b+1,0], x[b+1,1]
    float4 w  = W[e];         // W[0,0], W[0,1], W[1,0], W[1,1]
    float2 bv = b[e];

    float4 o;
    o.x = fmaf(xv.x, w.x, fmaf(xv.y, w.y, bv.x));  // out[b,0]
    o.y = fmaf(xv.x, w.z, fmaf(xv.y, w.w, bv.y));  // out[b,1]
    o.z = fmaf(xv.z, w.x, fmaf(xv.w, w.y, bv.x));  // out[b+1,0]
    o.w = fmaf(xv.z, w.z, fmaf(xv.w, w.w, bv.y));  // out[b+1,1]
    out[i] = o;
}

extern "C" void kernel_launch(void* const* d_in, const int* in_sizes, int n_in,
                              void* d_out, int out_size, void* d_ws, size_t ws_size,
                              hipStream_t stream) {
    const float4* x = (const float4*)d_in[0];  // (E,B,N) fp32
    const float4* W = (const float4*)d_in[1];  // (E,O,N) fp32
    const float2* b = (const float2*)d_in[2];  // (E,O)   fp32
    float4* out = (float4*)d_out;              // (E,B,O) fp32

    int total = out_size / 4;                  // 12,800,000 float4
    int block = 256;
    int grid = (total + block - 1) / block;    // 50,000 blocks
    plt_kernel<<<grid, block, 0, stream>>>(x, W, b, out, total);
}

// Round 4
// 322.868 us; speedup vs baseline: 1.0144x; 1.0144x over previous
//
#include <hip/hip_runtime.h>

// out[e,b,o] = sum_n x[e,b,n]*W[e,o,n] + b[e,o],  E=50000, B=512, N=O=2.
// x/out share the identical flat layout (E*512*2 floats = E*256 float4).
// One block per edge: blockIdx.x == e is wave-uniform -> W[e]/b[e] compile to
// scalar s_load (broadcast). Each thread moves exactly one float4 of x to one
// float4 of out: 2 VMEM ops/thread, perfectly coalesced, nontemporal (no reuse).
// Mandatory traffic: 204.8 MB read + 204.8 MB write -> ~65 us @ 6.3 TB/s.

typedef float vfloat4 __attribute__((ext_vector_type(4)));  // native clang vec
                                                            // (nontemporal builtins
                                                            //  reject HIP_vector_type)

__global__ __launch_bounds__(256) void plt_kernel(
    const vfloat4* __restrict__ x,
    const float4*  __restrict__ W,
    const float2*  __restrict__ b,
    vfloat4* __restrict__ out)
{
    const int e = blockIdx.x;                 // uniform -> scalar loads below
    const float4 w  = W[e];                   // W[0,0],W[0,1],W[1,0],W[1,1]
    const float2 bv = b[e];

    const int i = e * 256 + threadIdx.x;      // one float4 = 2 batch rows
    vfloat4 xv = __builtin_nontemporal_load(&x[i]);

    vfloat4 o;
    o.x = fmaf(xv.x, w.x, fmaf(xv.y, w.y, bv.x));  // out[b,  0]
    o.y = fmaf(xv.x, w.z, fmaf(xv.y, w.w, bv.y));  // out[b,  1]
    o.z = fmaf(xv.z, w.x, fmaf(xv.w, w.y, bv.x));  // out[b+1,0]
    o.w = fmaf(xv.z, w.z, fmaf(xv.w, w.w, bv.y));  // out[b+1,1]
    __builtin_nontemporal_store(o, &out[i]);
}

extern "C" void kernel_launch(void* const* d_in, const int* in_sizes, int n_in,
                              void* d_out, int out_size, void* d_ws, size_t ws_size,
                              hipStream_t stream) {
    const vfloat4* x = (const vfloat4*)d_in[0];  // (E,B,N) fp32
    const float4*  W = (const float4*)d_in[1];   // (E,O,N) fp32
    const float2*  b = (const float2*)d_in[2];   // (E,O)   fp32
    vfloat4* out = (vfloat4*)d_out;              // (E,B,O) fp32

    const int E = in_sizes[1] / 4;               // 50,000 edges
    plt_kernel<<<E, 256, 0, stream>>>(x, W, b, out);
}